// Round 1
// baseline (759.524 us; speedup 1.0000x reference)
//
#include <hip/hip_runtime.h>
#include <stdint.h>

typedef unsigned long long u64;
typedef float __attribute__((ext_vector_type(4))) fvec4;   // native vec for nontemporal

// workspace layout (bytes)
//  g      : u8  [16][512][512]           @ 0        (4 MiB)   (first 8 B reused as bar/cnt after k_sobel)
//  magdir : u16 [16][512][512]           @ 4 MiB    (8 MiB)   mag(11b) | dir<<12
//  weak   : u64 [16][512][8]             @ 12 MiB   (512 KiB)
//  strong : u64 [16][512][8]             @ 12.5 MiB (512 KiB)
//  edge   : u64 [16][512][8]             @ 13 MiB   (512 KiB)
#define MD_OFF   (4ull << 20)
#define WK_OFF   (12ull << 20)
#define ST_OFF   ((12ull << 20) + (512ull << 10))
#define ED_OFF   ((12ull << 20) + (1024ull << 10))

// ---------------- K1: gray = floor(clip(0.2989 x0 + 0.587 x1 + 0.114 x2)) ----
__global__ __launch_bounds__(256) void k_gray(const float* __restrict__ x,
                                              unsigned char* __restrict__ g) {
#pragma clang fp contract(off)
    const float C0 = (float)0.2989, C1 = (float)0.587, C2 = (float)0.114;
    int i   = blockIdx.x * 256 + threadIdx.x;   // 1,048,576 quads total
    int b   = i >> 16;                          // 65536 quads / image
    int rem = i & 65535;                        // h*128 + wq
    const float* xb = x + (size_t)b * 786432 + (size_t)rem * 4;
    float4 r0 = *(const float4*)(xb);
    float4 r1 = *(const float4*)(xb + 262144);
    float4 r2 = *(const float4*)(xb + 524288);
    float g0 = C0 * r0.x + C1 * r1.x + C2 * r2.x;   // ((a+b)+c) like numpy
    float g1 = C0 * r0.y + C1 * r1.y + C2 * r2.y;
    float g2 = C0 * r0.z + C1 * r1.z + C2 * r2.z;
    float g3 = C0 * r0.w + C1 * r1.w + C2 * r2.w;
    g0 = floorf(fminf(fmaxf(g0, 0.0f), 255.0f));
    g1 = floorf(fminf(fmaxf(g1, 0.0f), 255.0f));
    g2 = floorf(fminf(fmaxf(g2, 0.0f), 255.0f));
    g3 = floorf(fminf(fmaxf(g3, 0.0f), 255.0f));
    uchar4 st = make_uchar4((unsigned char)g0, (unsigned char)g1,
                            (unsigned char)g2, (unsigned char)g3);
    *(uchar4*)(g + (size_t)b * 262144 + (size_t)rem * 4) = st;
}

// ---------------- K2: Sobel (edge-replicate pad), mag = |gx|+|gy|, dir code --
__global__ __launch_bounds__(256) void k_sobel(const unsigned char* __restrict__ g,
                                               unsigned short* __restrict__ magdir) {
    const float TG22f = (float)0.4142135623730951;
    const float TG67f = (float)2.414213562373095;
    int i = blockIdx.x * 256 + threadIdx.x;     // 4,194,304 pixels
    int b = i >> 18;
    int r = (i >> 9) & 511;
    int w = i & 511;
    const unsigned char* gb = g + (size_t)b * 262144;
    int rm = r > 0 ? r - 1 : 0, rp = r < 511 ? r + 1 : 511;
    int wm = w > 0 ? w - 1 : 0, wp = w < 511 ? w + 1 : 511;
    int a00 = gb[rm * 512 + wm], a01 = gb[rm * 512 + w], a02 = gb[rm * 512 + wp];
    int a10 = gb[r  * 512 + wm],                          a12 = gb[r  * 512 + wp];
    int a20 = gb[rp * 512 + wm], a21 = gb[rp * 512 + w],  a22 = gb[rp * 512 + wp];
    int gx = a02 + 2 * a12 + a22 - a00 - 2 * a10 - a20;
    int gy = a20 + 2 * a21 + a22 - a00 - 2 * a01 - a02;
    int ax = gx < 0 ? -gx : gx;
    int ay = gy < 0 ? -gy : gy;
    int mag = ax + ay;                           // <= 2040, exact
    float fax = (float)ax, fay = (float)ay;
    unsigned dir;
    if (fay <= TG22f * fax)      dir = 0u;                       // horiz
    else if (fay > TG67f * fax)  dir = 1u;                       // vert
    else                         dir = (gx * gy >= 0) ? 2u : 3u; // diag
    magdir[i] = (unsigned short)(mag | (dir << 12));
}

// ---------------- K3: NMS + thresholds, ballot-pack weak/strong bitmasks -----
// Also resets the hysteresis grid-barrier epoch counter + change counter
// (they live in the dead gray-buffer region; k_hyst2 runs strictly after us).
__global__ __launch_bounds__(256) void k_nms(const unsigned short* __restrict__ magdir,
                                             u64* __restrict__ weakw,
                                             u64* __restrict__ strongw,
                                             unsigned* bar, unsigned* cnt) {
    if (blockIdx.x == 0 && threadIdx.x == 0) {
        __hip_atomic_store(bar, 0u, __ATOMIC_RELAXED, __HIP_MEMORY_SCOPE_AGENT);
        __hip_atomic_store(cnt, 0u, __ATOMIC_RELAXED, __HIP_MEMORY_SCOPE_AGENT);
    }
    int i = blockIdx.x * 256 + threadIdx.x;
    int b = i >> 18;
    int r = (i >> 9) & 511;
    int w = i & 511;
    const unsigned short* mb = magdir + (size_t)b * 262144;
    int md  = mb[r * 512 + w];
    int mag = md & 0x7FF;
    int dir = md >> 12;
    auto ldm = [&](int rr, int ww) -> int {
        if ((unsigned)rr > 511u || (unsigned)ww > 511u) return 0;  // zero pad
        return (int)(mb[rr * 512 + ww] & 0x7FF);
    };
    int n1, n2;
    if (dir == 0)      { n1 = ldm(r, w + 1);     n2 = ldm(r, w - 1); }
    else if (dir == 1) { n1 = ldm(r - 1, w);     n2 = ldm(r + 1, w); }
    else if (dir == 2) { n1 = ldm(r - 1, w - 1); n2 = ldm(r + 1, w + 1); }
    else               { n1 = ldm(r - 1, w + 1); n2 = ldm(r + 1, w - 1); }
    bool keep = (mag > n1) && (mag >= n2);
    int nms = keep ? mag : 0;
    u64 wb = __ballot(nms > 50);
    u64 sb = __ballot(nms > 150);
    int widx = ((b << 9) + r) * 8 + (w >> 6);
    int lane = threadIdx.x & 63;
    if (lane == 0) weakw[widx]   = wb;
    else if (lane == 1) strongw[widx] = sb;
}

// ---------------- K4: hysteresis flood fill, GRID-parallel ------------------
// Old version: 16 blocks (1 image / CU) = 6% of the machine for ~180 µs.
// New: 256 blocks x 256 thr = 16 images x 16 slabs of 32 rows. Per round:
//   - refresh 2 halo rows from neighbor slabs (agent-scope atomic loads)
//   - converge slab to local fixpoint in LDS (Jacobi + in-word runfill)
//   - publish own boundary rows (agent-scope atomic stores)
//   - 2 software grid barriers around a monotone change-counter read
// Termination: a round in which no block changed given freshly-read halos is
// the global fixpoint (monotone operator). Counter is never reset, and it is
// read strictly between two barriers, so all blocks agree on the exit round.
// Stale/fresh/torn u64 halo reads are all valid intermediate monotone states.
__device__ inline u64 upfill(u64 w, u64 s) {           // s subset of w
    return ((((w + s) ^ w) & w) | s);
}
__device__ inline u64 runfill(u64 w, u64 s) {
    u64 u = upfill(w, s);
    u64 d = __brevll(upfill(__brevll(w), __brevll(s)));
    return u | d;
}

#define HY_GRID 256u

// software grid barrier: epoch-counted, no reset. All HY_GRID blocks are
// trivially co-resident (2.5 KiB LDS, tiny VGPR, 256 blocks on 256 CUs).
__device__ __forceinline__ void gbar(unsigned* bar, unsigned target) {
    __syncthreads();                      // waits this block's mem ops too
    if (threadIdx.x == 0) {
        __threadfence();
        __hip_atomic_fetch_add(bar, 1u, __ATOMIC_ACQ_REL, __HIP_MEMORY_SCOPE_AGENT);
        while (__hip_atomic_load(bar, __ATOMIC_ACQUIRE, __HIP_MEMORY_SCOPE_AGENT) < target)
            __builtin_amdgcn_s_sleep(2);
        __threadfence();
    }
    __syncthreads();
}

__global__ __launch_bounds__(256) void k_hyst2(const u64* __restrict__ weakg,
                                               const u64* __restrict__ strongg,
                                               u64* __restrict__ curg,
                                               unsigned* bar, unsigned* cnt) {
    __shared__ u64 sc[34][9];            // rows -1..32 (halo), col pad 8->9
    __shared__ unsigned sbc;
    int blk = blockIdx.x;
    int b = blk >> 4, s = blk & 15;      // image, slab
    int t = threadIdx.x;
    int c = t & 7;                       // word column 0..7
    int r = t >> 3;                      // local row 0..31
    int grow = (s << 5) + r;             // global row
    size_t base = (size_t)b * 4096;
    size_t widx = base + (size_t)grow * 8 + c;
    u64 wv   = weakg[widx];
    u64 self = strongg[widx];
    sc[r + 1][c] = self;
    bool bdry = (r == 0) || (r == 31);
    if (bdry)                             // seed boundary rows for neighbors
        __hip_atomic_store(&curg[widx], self, __ATOMIC_RELEASE, __HIP_MEMORY_SCOPE_AGENT);
    unsigned ep = 0, prev = 0;
    ep += 1; gbar(bar, ep * HY_GRID);     // init visible grid-wide

    for (;;) {
        // ---- refresh halo rows from neighbor slabs ----
        if (t < 8) {
            u64 h = 0;
            if (s > 0)
                h = __hip_atomic_load(&curg[base + (size_t)((s << 5) - 1) * 8 + t],
                                      __ATOMIC_ACQUIRE, __HIP_MEMORY_SCOPE_AGENT);
            sc[0][t] = h;
        } else if (t < 16) {
            u64 h = 0;
            if (s < 15)
                h = __hip_atomic_load(&curg[base + (size_t)((s << 5) + 32) * 8 + (t - 8)],
                                      __ATOMIC_ACQUIRE, __HIP_MEMORY_SCOPE_AGENT);
            sc[33][t - 8] = h;
        }
        __syncthreads();
        // ---- local fixpoint (Jacobi over 32x8 words + in-word runfill) ----
        bool bchanged = false;
        for (;;) {
            u64 nv = self;
            if (self != wv) {             // not saturated
                int rr = r + 1;
                u64 um = sc[rr - 1][c], dm = sc[rr + 1][c];
                u64 lor = 0, ror_ = 0;
                if (c > 0) lor  = sc[rr - 1][c - 1] | sc[rr][c - 1] | sc[rr + 1][c - 1];
                if (c < 7) ror_ = sc[rr - 1][c + 1] | sc[rr][c + 1] | sc[rr + 1][c + 1];
                u64 vert = um | dm | self;
                u64 dil = vert | (vert << 1) | (vert >> 1)
                        | (lor >> 63) | (ror_ << 63);
                nv = runfill(wv, self | (wv & dil));
            }
            bool ch = (nv != self);
            if (ch) { sc[r + 1][c] = nv; self = nv; }
            if (!__syncthreads_or((int)ch)) break;
            bchanged = true;
        }
        // ---- publish boundary rows + change count ----
        if (bdry)
            __hip_atomic_store(&curg[widx], self, __ATOMIC_RELEASE, __HIP_MEMORY_SCOPE_AGENT);
        if (t == 0 && bchanged)
            __hip_atomic_fetch_add(cnt, 1u, __ATOMIC_ACQ_REL, __HIP_MEMORY_SCOPE_AGENT);
        ep += 1; gbar(bar, ep * HY_GRID);          // all round-k adds done
        if (t == 0)
            sbc = __hip_atomic_load(cnt, __ATOMIC_ACQUIRE, __HIP_MEMORY_SCOPE_AGENT);
        ep += 1; gbar(bar, ep * HY_GRID);          // all reads done before next adds
        unsigned cc = sbc;
        if (cc == prev) break;                     // globally consistent exit
        prev = cc;
    }
    curg[widx] = self;                   // final full-slab write for K5
}

// ---------------- K5: out[b,o,h,w] = relu(W.[x0,x1,x2,edge] + b) -------------
__global__ __launch_bounds__(256) void k_out(const float* __restrict__ x,
                                             const float* __restrict__ Wm,
                                             const float* __restrict__ bv,
                                             const u64* __restrict__ edgeg,
                                             float* __restrict__ out) {
    __shared__ float sW[128];
    __shared__ float sb[32];
    if (threadIdx.x < 128) sW[threadIdx.x] = Wm[threadIdx.x];
    if (threadIdx.x < 32)  sb[threadIdx.x] = bv[threadIdx.x];
    __syncthreads();
    int i   = blockIdx.x * 256 + threadIdx.x;   // 1,048,576 quads
    int b   = i >> 16;
    int rem = i & 65535;                        // h*128 + wq
    size_t pix = (size_t)rem * 4;               // h*512 + wq*4
    const float* xb = x + (size_t)b * 786432;
    float4 x0 = *(const float4*)(xb + pix);
    float4 x1 = *(const float4*)(xb + 262144 + pix);
    float4 x2 = *(const float4*)(xb + 524288 + pix);
    int r  = rem >> 7;
    int wq = rem & 127;
    u64 ew = edgeg[(((size_t)b * 512 + r) * 8) + (wq >> 4)];
    int sh = (wq & 15) * 4;
    float e0 = ((ew >> (sh + 0)) & 1ull) ? 255.0f : 0.0f;
    float e1 = ((ew >> (sh + 1)) & 1ull) ? 255.0f : 0.0f;
    float e2 = ((ew >> (sh + 2)) & 1ull) ? 255.0f : 0.0f;
    float e3 = ((ew >> (sh + 3)) & 1ull) ? 255.0f : 0.0f;
    float* ob = out + (size_t)b * 32 * 262144 + pix;
#pragma unroll 8
    for (int o = 0; o < 32; ++o) {
        float w0 = sW[o * 4 + 0], w1 = sW[o * 4 + 1];
        float w2 = sW[o * 4 + 2], w3 = sW[o * 4 + 3];
        float bb = sb[o];
        fvec4 v;
        v.x = fmaxf(w0 * x0.x + w1 * x1.x + w2 * x2.x + w3 * e0 + bb, 0.0f);
        v.y = fmaxf(w0 * x0.y + w1 * x1.y + w2 * x2.y + w3 * e1 + bb, 0.0f);
        v.z = fmaxf(w0 * x0.z + w1 * x1.z + w2 * x2.z + w3 * e2 + bb, 0.0f);
        v.w = fmaxf(w0 * x0.w + w1 * x1.w + w2 * x2.w + w3 * e3 + bb, 0.0f);
        __builtin_nontemporal_store(v, (fvec4*)(ob + (size_t)o * 262144));
    }
}

extern "C" void kernel_launch(void* const* d_in, const int* in_sizes, int n_in,
                              void* d_out, int out_size, void* d_ws, size_t ws_size,
                              hipStream_t stream) {
    const float* x  = (const float*)d_in[0];   // (16,3,512,512)
    const float* Wm = (const float*)d_in[1];   // (32,4)
    const float* bv = (const float*)d_in[2];   // (32,)
    float* out = (float*)d_out;                // (16,32,512,512)
    char* ws = (char*)d_ws;

    unsigned char*  g      = (unsigned char*)(ws);
    unsigned short* magdir = (unsigned short*)(ws + MD_OFF);
    u64* weakw   = (u64*)(ws + WK_OFF);
    u64* strongw = (u64*)(ws + ST_OFF);
    u64* edgew   = (u64*)(ws + ED_OFF);
    unsigned* bar = (unsigned*)(ws);           // reuse gray region (dead after k_sobel)
    unsigned* cnt = (unsigned*)(ws + 4);

    k_gray<<<4096, 256, 0, stream>>>(x, g);
    k_sobel<<<16384, 256, 0, stream>>>(g, magdir);
    k_nms<<<16384, 256, 0, stream>>>(magdir, weakw, strongw, bar, cnt);
    k_hyst2<<<(int)HY_GRID, 256, 0, stream>>>(weakw, strongw, edgew, bar, cnt);
    k_out<<<4096, 256, 0, stream>>>(x, Wm, bv, edgew, out);
}

// Round 2
// 660.379 us; speedup vs baseline: 1.1501x; 1.1501x over previous
//
#include <hip/hip_runtime.h>
#include <stdint.h>

typedef unsigned long long u64;
typedef float __attribute__((ext_vector_type(4))) fvec4;   // native vec for nontemporal

// workspace layout (bytes)
//  g      : u8  [16][512][512]           @ 0        (4 MiB)
//           (first 16*256 B reused as per-image hysteresis control blocks,
//            dead after k_sobel: img b -> bar @ b*256, cnt[2] @ b*256+128)
//  magdir : u16 [16][512][512]           @ 4 MiB    (8 MiB)   mag(11b) | dir<<12
//  weak   : u64 [16][512][8]             @ 12 MiB   (512 KiB)
//  strong : u64 [16][512][8]             @ 12.5 MiB (512 KiB)
//  edge   : u64 [16][512][8]             @ 13 MiB   (512 KiB)
#define MD_OFF   (4ull << 20)
#define WK_OFF   (12ull << 20)
#define ST_OFF   ((12ull << 20) + (512ull << 10))
#define ED_OFF   ((12ull << 20) + (1024ull << 10))

// ---------------- K1: gray = floor(clip(0.2989 x0 + 0.587 x1 + 0.114 x2)) ----
__global__ __launch_bounds__(256) void k_gray(const float* __restrict__ x,
                                              unsigned char* __restrict__ g) {
#pragma clang fp contract(off)
    const float C0 = (float)0.2989, C1 = (float)0.587, C2 = (float)0.114;
    int i   = blockIdx.x * 256 + threadIdx.x;   // 1,048,576 quads total
    int b   = i >> 16;                          // 65536 quads / image
    int rem = i & 65535;                        // h*128 + wq
    const float* xb = x + (size_t)b * 786432 + (size_t)rem * 4;
    float4 r0 = *(const float4*)(xb);
    float4 r1 = *(const float4*)(xb + 262144);
    float4 r2 = *(const float4*)(xb + 524288);
    float g0 = C0 * r0.x + C1 * r1.x + C2 * r2.x;   // ((a+b)+c) like numpy
    float g1 = C0 * r0.y + C1 * r1.y + C2 * r2.y;
    float g2 = C0 * r0.z + C1 * r1.z + C2 * r2.z;
    float g3 = C0 * r0.w + C1 * r1.w + C2 * r2.w;
    g0 = floorf(fminf(fmaxf(g0, 0.0f), 255.0f));
    g1 = floorf(fminf(fmaxf(g1, 0.0f), 255.0f));
    g2 = floorf(fminf(fmaxf(g2, 0.0f), 255.0f));
    g3 = floorf(fminf(fmaxf(g3, 0.0f), 255.0f));
    uchar4 st = make_uchar4((unsigned char)g0, (unsigned char)g1,
                            (unsigned char)g2, (unsigned char)g3);
    *(uchar4*)(g + (size_t)b * 262144 + (size_t)rem * 4) = st;
}

// ---------------- K2: Sobel (edge-replicate pad), mag = |gx|+|gy|, dir code --
__global__ __launch_bounds__(256) void k_sobel(const unsigned char* __restrict__ g,
                                               unsigned short* __restrict__ magdir) {
    const float TG22f = (float)0.4142135623730951;
    const float TG67f = (float)2.414213562373095;
    int i = blockIdx.x * 256 + threadIdx.x;     // 4,194,304 pixels
    int b = i >> 18;
    int r = (i >> 9) & 511;
    int w = i & 511;
    const unsigned char* gb = g + (size_t)b * 262144;
    int rm = r > 0 ? r - 1 : 0, rp = r < 511 ? r + 1 : 511;
    int wm = w > 0 ? w - 1 : 0, wp = w < 511 ? w + 1 : 511;
    int a00 = gb[rm * 512 + wm], a01 = gb[rm * 512 + w], a02 = gb[rm * 512 + wp];
    int a10 = gb[r  * 512 + wm],                          a12 = gb[r  * 512 + wp];
    int a20 = gb[rp * 512 + wm], a21 = gb[rp * 512 + w],  a22 = gb[rp * 512 + wp];
    int gx = a02 + 2 * a12 + a22 - a00 - 2 * a10 - a20;
    int gy = a20 + 2 * a21 + a22 - a00 - 2 * a01 - a02;
    int ax = gx < 0 ? -gx : gx;
    int ay = gy < 0 ? -gy : gy;
    int mag = ax + ay;                           // <= 2040, exact
    float fax = (float)ax, fay = (float)ay;
    unsigned dir;
    if (fay <= TG22f * fax)      dir = 0u;                       // horiz
    else if (fay > TG67f * fax)  dir = 1u;                       // vert
    else                         dir = (gx * gy >= 0) ? 2u : 3u; // diag
    magdir[i] = (unsigned short)(mag | (dir << 12));
}

// ---------------- K3: NMS + thresholds, ballot-pack weak/strong bitmasks -----
// Blocks 0..15 also reset image-blockIdx's hysteresis control block (plain
// stores; kernel-boundary ordering makes them visible to k_hyst3).
__global__ __launch_bounds__(256) void k_nms(const unsigned short* __restrict__ magdir,
                                             u64* __restrict__ weakw,
                                             u64* __restrict__ strongw,
                                             unsigned* __restrict__ ctl) {
    if (blockIdx.x < 16 && threadIdx.x == 0) {
        unsigned* c = ctl + blockIdx.x * 64;   // 256 B per image
        c[0]  = 0;                             // bar
        c[32] = 0;                             // cnt[0]  (separate 128B line)
        c[33] = 0;                             // cnt[1]
    }
    int i = blockIdx.x * 256 + threadIdx.x;
    int b = i >> 18;
    int r = (i >> 9) & 511;
    int w = i & 511;
    const unsigned short* mb = magdir + (size_t)b * 262144;
    int md  = mb[r * 512 + w];
    int mag = md & 0x7FF;
    int dir = md >> 12;
    auto ldm = [&](int rr, int ww) -> int {
        if ((unsigned)rr > 511u || (unsigned)ww > 511u) return 0;  // zero pad
        return (int)(mb[rr * 512 + ww] & 0x7FF);
    };
    int n1, n2;
    if (dir == 0)      { n1 = ldm(r, w + 1);     n2 = ldm(r, w - 1); }
    else if (dir == 1) { n1 = ldm(r - 1, w);     n2 = ldm(r + 1, w); }
    else if (dir == 2) { n1 = ldm(r - 1, w - 1); n2 = ldm(r + 1, w + 1); }
    else               { n1 = ldm(r - 1, w + 1); n2 = ldm(r + 1, w - 1); }
    bool keep = (mag > n1) && (mag >= n2);
    int nms = keep ? mag : 0;
    u64 wb = __ballot(nms > 50);
    u64 sb = __ballot(nms > 150);
    int widx = ((b << 9) + r) * 8 + (w >> 6);
    int lane = threadIdx.x & 63;
    if (lane == 0) weakw[widx]   = wb;
    else if (lane == 1) strongw[widx] = sb;
}

// ---------------- K4: hysteresis flood fill, per-image grid-parallel --------
// Round-0 lesson: ONE barrier over 256 blocks on one cache line cost ~µs×
// hundreds (k_hyst2 ~390 µs implied). This version: 16 images x 16 slabs of
// 32 rows; each image has its OWN barrier + ping-pong change counters on its
// own 256B control block -> 16 participants/barrier, images exit
// independently, one barrier per round (ping-pong counters make the single
// barrier sufficient: round-k adds hit cnt[k&1]; barrier k orders them before
// the reads; round-k+2 adds to the same counter are gated by barrier k+1
// which requires all round-k reads done).
// Monotone fixpoint => stale/fresh/torn u64 halo reads are all valid
// intermediate states; termination round is read at a write-quiesced point so
// all 16 blocks of an image agree on the exit round.
__device__ inline u64 upfill(u64 w, u64 s) {           // s subset of w
    return ((((w + s) ^ w) & w) | s);
}
__device__ inline u64 runfill(u64 w, u64 s) {
    u64 u = upfill(w, s);
    u64 d = __brevll(upfill(__brevll(w), __brevll(s)));
    return u | d;
}

// per-image barrier: epoch-counted, no reset, 16 participants.
__device__ __forceinline__ void gbar(unsigned* bar, unsigned target) {
    __syncthreads();                      // block's LDS + mem ops ordered
    if (threadIdx.x == 0) {
        __threadfence();
        __hip_atomic_fetch_add(bar, 1u, __ATOMIC_ACQ_REL, __HIP_MEMORY_SCOPE_AGENT);
        while (__hip_atomic_load(bar, __ATOMIC_ACQUIRE, __HIP_MEMORY_SCOPE_AGENT) < target)
            __builtin_amdgcn_s_sleep(1);
        __threadfence();
    }
    __syncthreads();
}

__global__ __launch_bounds__(256) void k_hyst3(const u64* __restrict__ weakg,
                                               const u64* __restrict__ strongg,
                                               u64* __restrict__ curg,
                                               unsigned* __restrict__ ctl) {
    __shared__ u64 sc[34][9];            // rows -1..32 (halo), col pad 8->9
    __shared__ unsigned sbc;
    int blk = blockIdx.x;
    int b = blk >> 4, s = blk & 15;      // image, slab
    unsigned* bar = ctl + b * 64;        // per-image control block (256 B)
    unsigned* cnt = bar + 32;            // cnt[0], cnt[1] on separate line
    int t = threadIdx.x;
    int c = t & 7;                       // word column 0..7
    int r = t >> 3;                      // local row 0..31
    int grow = (s << 5) + r;             // global row
    size_t base = (size_t)b * 4096;
    size_t widx = base + (size_t)grow * 8 + c;
    u64 wv   = weakg[widx];
    u64 self = strongg[widx];
    sc[r + 1][c] = self;
    bool bdry = (r == 0) || (r == 31);
    if (bdry)                             // seed boundary rows for neighbors
        __hip_atomic_store(&curg[widx], self, __ATOMIC_RELEASE, __HIP_MEMORY_SCOPE_AGENT);
    unsigned ep = 1;
    gbar(bar, ep * 16u);                  // seeds visible image-wide
    unsigned prev0 = 0, prev1 = 0;
    int p = 0;

    for (;;) {
        // ---- refresh halo rows from neighbor slabs ----
        if (t < 8) {
            u64 h = 0;
            if (s > 0)
                h = __hip_atomic_load(&curg[base + (size_t)((s << 5) - 1) * 8 + t],
                                      __ATOMIC_ACQUIRE, __HIP_MEMORY_SCOPE_AGENT);
            sc[0][t] = h;
        } else if (t < 16) {
            u64 h = 0;
            if (s < 15)
                h = __hip_atomic_load(&curg[base + (size_t)((s << 5) + 32) * 8 + (t - 8)],
                                      __ATOMIC_ACQUIRE, __HIP_MEMORY_SCOPE_AGENT);
            sc[33][t - 8] = h;
        }
        __syncthreads();
        // ---- local fixpoint (Jacobi over 32x8 words + in-word runfill) ----
        bool bchanged = false;
        for (;;) {
            u64 nv = self;
            if (self != wv) {             // not saturated
                int rr = r + 1;
                u64 um = sc[rr - 1][c], dm = sc[rr + 1][c];
                u64 lor = 0, ror_ = 0;
                if (c > 0) lor  = sc[rr - 1][c - 1] | sc[rr][c - 1] | sc[rr + 1][c - 1];
                if (c < 7) ror_ = sc[rr - 1][c + 1] | sc[rr][c + 1] | sc[rr + 1][c + 1];
                u64 vert = um | dm | self;
                u64 dil = vert | (vert << 1) | (vert >> 1)
                        | (lor >> 63) | (ror_ << 63);
                nv = runfill(wv, self | (wv & dil));
            }
            bool ch = (nv != self);
            if (ch) { sc[r + 1][c] = nv; self = nv; }
            if (!__syncthreads_or((int)ch)) break;
            bchanged = true;
        }
        // ---- publish boundary rows + per-round change count (ping-pong) ----
        if (bdry)
            __hip_atomic_store(&curg[widx], self, __ATOMIC_RELEASE, __HIP_MEMORY_SCOPE_AGENT);
        if (t == 0 && bchanged)
            __hip_atomic_fetch_add(&cnt[p], 1u, __ATOMIC_ACQ_REL, __HIP_MEMORY_SCOPE_AGENT);
        ep += 1; gbar(bar, ep * 16u);     // all round-k adds + publishes done
        if (t == 0)
            sbc = __hip_atomic_load(&cnt[p], __ATOMIC_ACQUIRE, __HIP_MEMORY_SCOPE_AGENT);
        __syncthreads();                  // sbc visible block-wide
        unsigned cc = sbc;
        unsigned& prv = p ? prev1 : prev0;
        if (cc == prv) break;             // image-wide consistent exit
        prv = cc;
        p ^= 1;
    }
    curg[widx] = self;                   // final full-slab write for K5
}

// ---------------- K5: out[b,o,h,w] = relu(W.[x0,x1,x2,edge] + b) -------------
__global__ __launch_bounds__(256) void k_out(const float* __restrict__ x,
                                             const float* __restrict__ Wm,
                                             const float* __restrict__ bv,
                                             const u64* __restrict__ edgeg,
                                             float* __restrict__ out) {
    __shared__ float sW[128];
    __shared__ float sb[32];
    if (threadIdx.x < 128) sW[threadIdx.x] = Wm[threadIdx.x];
    if (threadIdx.x < 32)  sb[threadIdx.x] = bv[threadIdx.x];
    __syncthreads();
    int i   = blockIdx.x * 256 + threadIdx.x;   // 1,048,576 quads
    int b   = i >> 16;
    int rem = i & 65535;                        // h*128 + wq
    size_t pix = (size_t)rem * 4;               // h*512 + wq*4
    const float* xb = x + (size_t)b * 786432;
    float4 x0 = *(const float4*)(xb + pix);
    float4 x1 = *(const float4*)(xb + 262144 + pix);
    float4 x2 = *(const float4*)(xb + 524288 + pix);
    int r  = rem >> 7;
    int wq = rem & 127;
    u64 ew = edgeg[(((size_t)b * 512 + r) * 8) + (wq >> 4)];
    int sh = (wq & 15) * 4;
    float e0 = ((ew >> (sh + 0)) & 1ull) ? 255.0f : 0.0f;
    float e1 = ((ew >> (sh + 1)) & 1ull) ? 255.0f : 0.0f;
    float e2 = ((ew >> (sh + 2)) & 1ull) ? 255.0f : 0.0f;
    float e3 = ((ew >> (sh + 3)) & 1ull) ? 255.0f : 0.0f;
    float* ob = out + (size_t)b * 32 * 262144 + pix;
#pragma unroll 8
    for (int o = 0; o < 32; ++o) {
        float w0 = sW[o * 4 + 0], w1 = sW[o * 4 + 1];
        float w2 = sW[o * 4 + 2], w3 = sW[o * 4 + 3];
        float bb = sb[o];
        fvec4 v;
        v.x = fmaxf(w0 * x0.x + w1 * x1.x + w2 * x2.x + w3 * e0 + bb, 0.0f);
        v.y = fmaxf(w0 * x0.y + w1 * x1.y + w2 * x2.y + w3 * e1 + bb, 0.0f);
        v.z = fmaxf(w0 * x0.z + w1 * x1.z + w2 * x2.z + w3 * e2 + bb, 0.0f);
        v.w = fmaxf(w0 * x0.w + w1 * x1.w + w2 * x2.w + w3 * e3 + bb, 0.0f);
        __builtin_nontemporal_store(v, (fvec4*)(ob + (size_t)o * 262144));
    }
}

extern "C" void kernel_launch(void* const* d_in, const int* in_sizes, int n_in,
                              void* d_out, int out_size, void* d_ws, size_t ws_size,
                              hipStream_t stream) {
    const float* x  = (const float*)d_in[0];   // (16,3,512,512)
    const float* Wm = (const float*)d_in[1];   // (32,4)
    const float* bv = (const float*)d_in[2];   // (32,)
    float* out = (float*)d_out;                // (16,32,512,512)
    char* ws = (char*)d_ws;

    unsigned char*  g      = (unsigned char*)(ws);
    unsigned short* magdir = (unsigned short*)(ws + MD_OFF);
    u64* weakw   = (u64*)(ws + WK_OFF);
    u64* strongw = (u64*)(ws + ST_OFF);
    u64* edgew   = (u64*)(ws + ED_OFF);
    unsigned* ctl = (unsigned*)(ws);           // per-image control blocks (dead gray region)

    k_gray<<<4096, 256, 0, stream>>>(x, g);
    k_sobel<<<16384, 256, 0, stream>>>(g, magdir);
    k_nms<<<16384, 256, 0, stream>>>(magdir, weakw, strongw, ctl);
    k_hyst3<<<256, 256, 0, stream>>>(weakw, strongw, edgew, ctl);
    k_out<<<4096, 256, 0, stream>>>(x, Wm, bv, edgew, out);
}

// Round 3
// 600.983 us; speedup vs baseline: 1.2638x; 1.0988x over previous
//
#include <hip/hip_runtime.h>
#include <stdint.h>

typedef unsigned long long u64;
typedef float __attribute__((ext_vector_type(4))) fvec4;   // native vec for nontemporal

// workspace layout (bytes)
//  g      : u8  [16][512][512]           @ 0        (4 MiB)
//  magdir : u16 [16][512][512]           @ 4 MiB    (8 MiB)   mag(11b) | dir<<12
//  weak   : u64 [16][512][8]             @ 12 MiB   (512 KiB)
//  strong : u64 [16][512][8]             @ 12.5 MiB (512 KiB)
//  edge   : u64 [16][512][8]             @ 13 MiB   (512 KiB)
#define MD_OFF   (4ull << 20)
#define WK_OFF   (12ull << 20)
#define ST_OFF   ((12ull << 20) + (512ull << 10))
#define ED_OFF   ((12ull << 20) + (1024ull << 10))

// ---------------- K1: gray = floor(clip(0.2989 x0 + 0.587 x1 + 0.114 x2)) ----
__global__ __launch_bounds__(256) void k_gray(const float* __restrict__ x,
                                              unsigned char* __restrict__ g) {
#pragma clang fp contract(off)
    const float C0 = (float)0.2989, C1 = (float)0.587, C2 = (float)0.114;
    int i   = blockIdx.x * 256 + threadIdx.x;   // 1,048,576 quads total
    int b   = i >> 16;                          // 65536 quads / image
    int rem = i & 65535;                        // h*128 + wq
    const float* xb = x + (size_t)b * 786432 + (size_t)rem * 4;
    float4 r0 = *(const float4*)(xb);
    float4 r1 = *(const float4*)(xb + 262144);
    float4 r2 = *(const float4*)(xb + 524288);
    float g0 = C0 * r0.x + C1 * r1.x + C2 * r2.x;   // ((a+b)+c) like numpy
    float g1 = C0 * r0.y + C1 * r1.y + C2 * r2.y;
    float g2 = C0 * r0.z + C1 * r1.z + C2 * r2.z;
    float g3 = C0 * r0.w + C1 * r1.w + C2 * r2.w;
    g0 = floorf(fminf(fmaxf(g0, 0.0f), 255.0f));
    g1 = floorf(fminf(fmaxf(g1, 0.0f), 255.0f));
    g2 = floorf(fminf(fmaxf(g2, 0.0f), 255.0f));
    g3 = floorf(fminf(fmaxf(g3, 0.0f), 255.0f));
    uchar4 st = make_uchar4((unsigned char)g0, (unsigned char)g1,
                            (unsigned char)g2, (unsigned char)g3);
    *(uchar4*)(g + (size_t)b * 262144 + (size_t)rem * 4) = st;
}

// ---------------- K2: Sobel (edge-replicate pad), mag = |gx|+|gy|, dir code --
__global__ __launch_bounds__(256) void k_sobel(const unsigned char* __restrict__ g,
                                               unsigned short* __restrict__ magdir) {
    const float TG22f = (float)0.4142135623730951;
    const float TG67f = (float)2.414213562373095;
    int i = blockIdx.x * 256 + threadIdx.x;     // 4,194,304 pixels
    int b = i >> 18;
    int r = (i >> 9) & 511;
    int w = i & 511;
    const unsigned char* gb = g + (size_t)b * 262144;
    int rm = r > 0 ? r - 1 : 0, rp = r < 511 ? r + 1 : 511;
    int wm = w > 0 ? w - 1 : 0, wp = w < 511 ? w + 1 : 511;
    int a00 = gb[rm * 512 + wm], a01 = gb[rm * 512 + w], a02 = gb[rm * 512 + wp];
    int a10 = gb[r  * 512 + wm],                          a12 = gb[r  * 512 + wp];
    int a20 = gb[rp * 512 + wm], a21 = gb[rp * 512 + w],  a22 = gb[rp * 512 + wp];
    int gx = a02 + 2 * a12 + a22 - a00 - 2 * a10 - a20;
    int gy = a20 + 2 * a21 + a22 - a00 - 2 * a01 - a02;
    int ax = gx < 0 ? -gx : gx;
    int ay = gy < 0 ? -gy : gy;
    int mag = ax + ay;                           // <= 2040, exact
    float fax = (float)ax, fay = (float)ay;
    unsigned dir;
    if (fay <= TG22f * fax)      dir = 0u;                       // horiz
    else if (fay > TG67f * fax)  dir = 1u;                       // vert
    else                         dir = (gx * gy >= 0) ? 2u : 3u; // diag
    magdir[i] = (unsigned short)(mag | (dir << 12));
}

// ---------------- K3: NMS + thresholds, ballot-pack weak/strong bitmasks -----
__global__ __launch_bounds__(256) void k_nms(const unsigned short* __restrict__ magdir,
                                             u64* __restrict__ weakw,
                                             u64* __restrict__ strongw) {
    int i = blockIdx.x * 256 + threadIdx.x;
    int b = i >> 18;
    int r = (i >> 9) & 511;
    int w = i & 511;
    const unsigned short* mb = magdir + (size_t)b * 262144;
    int md  = mb[r * 512 + w];
    int mag = md & 0x7FF;
    int dir = md >> 12;
    auto ldm = [&](int rr, int ww) -> int {
        if ((unsigned)rr > 511u || (unsigned)ww > 511u) return 0;  // zero pad
        return (int)(mb[rr * 512 + ww] & 0x7FF);
    };
    int n1, n2;
    if (dir == 0)      { n1 = ldm(r, w + 1);     n2 = ldm(r, w - 1); }
    else if (dir == 1) { n1 = ldm(r - 1, w);     n2 = ldm(r + 1, w); }
    else if (dir == 2) { n1 = ldm(r - 1, w - 1); n2 = ldm(r + 1, w + 1); }
    else               { n1 = ldm(r - 1, w + 1); n2 = ldm(r + 1, w - 1); }
    bool keep = (mag > n1) && (mag >= n2);
    int nms = keep ? mag : 0;
    u64 wb = __ballot(nms > 50);
    u64 sb = __ballot(nms > 150);
    int widx = ((b << 9) + r) * 8 + (w >> 6);
    int lane = threadIdx.x & 63;
    if (lane == 0) weakw[widx]   = wb;
    else if (lane == 1) strongw[widx] = sb;
}

// ---------------- K4: hysteresis flood fill, block-per-image ----------------
// Round 0/1 lesson: cross-block sync (global barriers) loses to 16 independent
// blocks regardless of barrier scope — the cost is PROPAGATION LATENCY.
// Old slow axis: horizontal cross-word fill moved 1 u64 word (64 px) per
// down/up sweep-pair (~50 rounds on percolation-like speckle). This version
// adds a full-row HORIZONTAL fill sweep each round: 512 threads own one row
// each (8 u64 in regs), two-pass carry fill (L->R, R->L) with in-word
// runfill => horizontal propagation is image-width per round. Rounds drop to
// ~(# direction reversals of worst chain).
// Monotone fixpoint of cur |= weak & dilate3x3(cur): stale LDS reads across
// phases are valid intermediate states; exit only when a full round (V+H)
// changes nothing.
__device__ inline u64 upfill(u64 w, u64 s) {           // s subset of w
    return ((((w + s) ^ w) & w) | s);
}
__device__ inline u64 runfill(u64 w, u64 s) {
    u64 u = upfill(w, s);
    u64 d = __brevll(upfill(__brevll(w), __brevll(s)));
    return u | d;
}

#define HST 9   // padded LDS row stride (words)

__global__ __launch_bounds__(1024) void k_hyst(const u64* __restrict__ weakg,
                                               const u64* __restrict__ strongg,
                                               u64* __restrict__ edgeg) {
    __shared__ u64 sc[512 * HST];   // cur, row*HST+col  (36.9 KiB)
    __shared__ int sflag;
    int b = blockIdx.x;
    int t = threadIdx.x;
    const u64* wk = weakg + (size_t)b * 4096;
    const u64* st = strongg + (size_t)b * 4096;
#pragma unroll
    for (int i = 0; i < 4; ++i) {
        int ig = i * 1024 + t;              // coalesced global
        int r = ig >> 3, c = ig & 7;
        sc[r * HST + c] = st[ig];
    }
    int c  = t & 7;
    int r0 = (t >> 3) * 4;                  // 4 rows per thread (V phase)
    u64 wreg[4];
#pragma unroll
    for (int j = 0; j < 4; ++j) wreg[j] = wk[(r0 + j) * 8 + c];
    if (t == 0) sflag = 0;
    const bool hasL = c > 0, hasR = c < 7;
    __syncthreads();

    for (;;) {
        bool ch = false;
        // ---- DOWN sweep ----
        {
            u64 carry = (r0 > 0) ? sc[(r0 - 1) * HST + c] : 0;
#pragma unroll
            for (int j = 0; j < 4; ++j) {
                int r = r0 + j;
                int idx = r * HST + c;
                u64 wv = wreg[j];
                u64 self = sc[idx];
                if (self == wv) { carry = self; continue; }
                u64 dm = (r < 511) ? sc[idx + HST] : 0;
                u64 lor = 0, ror_ = 0;
                if (hasL) {
                    u64 lm = sc[idx - 1];
                    u64 lu = (r > 0)   ? sc[idx - HST - 1] : 0;
                    u64 ld = (r < 511) ? sc[idx + HST - 1] : 0;
                    lor = lm | lu | ld;
                }
                if (hasR) {
                    u64 rm = sc[idx + 1];
                    u64 ru = (r > 0)   ? sc[idx - HST + 1] : 0;
                    u64 rd = (r < 511) ? sc[idx + HST + 1] : 0;
                    ror_ = rm | ru | rd;
                }
                u64 vert = carry | dm | self;
                u64 dil = vert | (vert << 1) | (vert >> 1)
                        | (lor >> 63) | (ror_ << 63);
                u64 nv = runfill(wv, self | (wv & dil));
                if (nv != self) { sc[idx] = nv; ch = true; }
                carry = nv;
            }
        }
        // ---- UP sweep ----
        {
            u64 carry = (r0 + 4 < 512) ? sc[(r0 + 4) * HST + c] : 0;
#pragma unroll
            for (int j = 3; j >= 0; --j) {
                int r = r0 + j;
                int idx = r * HST + c;
                u64 wv = wreg[j];
                u64 self = sc[idx];
                if (self == wv) { carry = self; continue; }
                u64 um = (r > 0) ? sc[idx - HST] : 0;
                u64 lor = 0, ror_ = 0;
                if (hasL) {
                    u64 lm = sc[idx - 1];
                    u64 lu = (r > 0)   ? sc[idx - HST - 1] : 0;
                    u64 ld = (r < 511) ? sc[idx + HST - 1] : 0;
                    lor = lm | lu | ld;
                }
                if (hasR) {
                    u64 rm = sc[idx + 1];
                    u64 ru = (r > 0)   ? sc[idx - HST + 1] : 0;
                    u64 rd = (r < 511) ? sc[idx + HST + 1] : 0;
                    ror_ = rm | ru | rd;
                }
                u64 vert = um | carry | self;
                u64 dil = vert | (vert << 1) | (vert >> 1)
                        | (lor >> 63) | (ror_ << 63);
                u64 nv = runfill(wv, self | (wv & dil));
                if (nv != self) { sc[idx] = nv; ch = true; }
                carry = nv;
            }
        }
        // ---- H sweep: full-row horizontal fill, image-width per round ----
        __syncthreads();                    // V writes visible to row owners
        if (t < 512) {
            u64 m[8], f[8], wv8[8];
            const u64* wr = wk + (size_t)t * 8;
#pragma unroll
            for (int c2 = 0; c2 < 8; ++c2) m[c2] = sc[t * HST + c2];
#pragma unroll
            for (int c2 = 0; c2 < 8; ++c2) wv8[c2] = wr[c2];   // L2-resident
            u64 carry = 0;
#pragma unroll
            for (int c2 = 0; c2 < 8; ++c2) {       // L -> R
                u64 s2 = m[c2] | (carry & wv8[c2] & 1ull);
                f[c2] = runfill(wv8[c2], s2);
                carry = f[c2] >> 63;
            }
            carry = 0;
#pragma unroll
            for (int c2 = 7; c2 >= 0; --c2) {      // R -> L
                u64 s2 = f[c2] | ((carry << 63) & wv8[c2]);
                f[c2] = runfill(wv8[c2], s2);
                carry = f[c2] & 1ull;
            }
#pragma unroll
            for (int c2 = 0; c2 < 8; ++c2) {
                if (f[c2] != m[c2]) { sc[t * HST + c2] = f[c2]; ch = true; }
            }
        }
        if (ch) sflag = 1;
        __syncthreads();
        bool stop = (sflag == 0);
        __syncthreads();                    // all reads done before reset
        if (stop) break;
        if (t == 0) sflag = 0;
        __syncthreads();                    // reset visible before next sweeps
    }

    u64* eg = edgeg + (size_t)b * 4096;
#pragma unroll
    for (int i = 0; i < 4; ++i) {
        int ig = i * 1024 + t;
        int r = ig >> 3, cc = ig & 7;
        eg[ig] = sc[r * HST + cc];
    }
}

// ---------------- K5: out[b,o,h,w] = relu(W.[x0,x1,x2,edge] + b) -------------
__global__ __launch_bounds__(256) void k_out(const float* __restrict__ x,
                                             const float* __restrict__ Wm,
                                             const float* __restrict__ bv,
                                             const u64* __restrict__ edgeg,
                                             float* __restrict__ out) {
    __shared__ float sW[128];
    __shared__ float sb[32];
    if (threadIdx.x < 128) sW[threadIdx.x] = Wm[threadIdx.x];
    if (threadIdx.x < 32)  sb[threadIdx.x] = bv[threadIdx.x];
    __syncthreads();
    int i   = blockIdx.x * 256 + threadIdx.x;   // 1,048,576 quads
    int b   = i >> 16;
    int rem = i & 65535;                        // h*128 + wq
    size_t pix = (size_t)rem * 4;               // h*512 + wq*4
    const float* xb = x + (size_t)b * 786432;
    float4 x0 = *(const float4*)(xb + pix);
    float4 x1 = *(const float4*)(xb + 262144 + pix);
    float4 x2 = *(const float4*)(xb + 524288 + pix);
    int r  = rem >> 7;
    int wq = rem & 127;
    u64 ew = edgeg[(((size_t)b * 512 + r) * 8) + (wq >> 4)];
    int sh = (wq & 15) * 4;
    float e0 = ((ew >> (sh + 0)) & 1ull) ? 255.0f : 0.0f;
    float e1 = ((ew >> (sh + 1)) & 1ull) ? 255.0f : 0.0f;
    float e2 = ((ew >> (sh + 2)) & 1ull) ? 255.0f : 0.0f;
    float e3 = ((ew >> (sh + 3)) & 1ull) ? 255.0f : 0.0f;
    float* ob = out + (size_t)b * 32 * 262144 + pix;
#pragma unroll 8
    for (int o = 0; o < 32; ++o) {
        float w0 = sW[o * 4 + 0], w1 = sW[o * 4 + 1];
        float w2 = sW[o * 4 + 2], w3 = sW[o * 4 + 3];
        float bb = sb[o];
        fvec4 v;
        v.x = fmaxf(w0 * x0.x + w1 * x1.x + w2 * x2.x + w3 * e0 + bb, 0.0f);
        v.y = fmaxf(w0 * x0.y + w1 * x1.y + w2 * x2.y + w3 * e1 + bb, 0.0f);
        v.z = fmaxf(w0 * x0.z + w1 * x1.z + w2 * x2.z + w3 * e2 + bb, 0.0f);
        v.w = fmaxf(w0 * x0.w + w1 * x1.w + w2 * x2.w + w3 * e3 + bb, 0.0f);
        __builtin_nontemporal_store(v, (fvec4*)(ob + (size_t)o * 262144));
    }
}

extern "C" void kernel_launch(void* const* d_in, const int* in_sizes, int n_in,
                              void* d_out, int out_size, void* d_ws, size_t ws_size,
                              hipStream_t stream) {
    const float* x  = (const float*)d_in[0];   // (16,3,512,512)
    const float* Wm = (const float*)d_in[1];   // (32,4)
    const float* bv = (const float*)d_in[2];   // (32,)
    float* out = (float*)d_out;                // (16,32,512,512)
    char* ws = (char*)d_ws;

    unsigned char*  g      = (unsigned char*)(ws);
    unsigned short* magdir = (unsigned short*)(ws + MD_OFF);
    u64* weakw   = (u64*)(ws + WK_OFF);
    u64* strongw = (u64*)(ws + ST_OFF);
    u64* edgew   = (u64*)(ws + ED_OFF);

    k_gray<<<4096, 256, 0, stream>>>(x, g);
    k_sobel<<<16384, 256, 0, stream>>>(g, magdir);
    k_nms<<<16384, 256, 0, stream>>>(magdir, weakw, strongw);
    k_hyst<<<16, 1024, 0, stream>>>(weakw, strongw, edgew);
    k_out<<<4096, 256, 0, stream>>>(x, Wm, bv, edgew, out);
}

// Round 5
// 598.599 us; speedup vs baseline: 1.2688x; 1.0040x over previous
//
#include <hip/hip_runtime.h>
#include <stdint.h>

typedef unsigned long long u64;
typedef float __attribute__((ext_vector_type(4))) fvec4;   // native vec for nontemporal

// workspace layout (bytes)
//  g      : u8  [16][512][512]           @ 0        (4 MiB)
//  magdir : u16 [16][512][512]           @ 4 MiB    (8 MiB)   mag(11b) | dir<<12
//  weak   : u64 [16][512][8]             @ 12 MiB   (512 KiB)
//  strong : u64 [16][512][8]             @ 12.5 MiB (512 KiB)
//  edge   : u64 [16][512][8]             @ 13 MiB   (512 KiB)
#define MD_OFF   (4ull << 20)
#define WK_OFF   (12ull << 20)
#define ST_OFF   ((12ull << 20) + (512ull << 10))
#define ED_OFF   ((12ull << 20) + (1024ull << 10))

// ---------------- K1: gray = floor(clip(0.2989 x0 + 0.587 x1 + 0.114 x2)) ----
__global__ __launch_bounds__(256) void k_gray(const float* __restrict__ x,
                                              unsigned char* __restrict__ g) {
#pragma clang fp contract(off)
    const float C0 = (float)0.2989, C1 = (float)0.587, C2 = (float)0.114;
    int i   = blockIdx.x * 256 + threadIdx.x;   // 1,048,576 quads total
    int b   = i >> 16;                          // 65536 quads / image
    int rem = i & 65535;                        // h*128 + wq
    const float* xb = x + (size_t)b * 786432 + (size_t)rem * 4;
    float4 r0 = *(const float4*)(xb);
    float4 r1 = *(const float4*)(xb + 262144);
    float4 r2 = *(const float4*)(xb + 524288);
    float g0 = C0 * r0.x + C1 * r1.x + C2 * r2.x;   // ((a+b)+c) like numpy
    float g1 = C0 * r0.y + C1 * r1.y + C2 * r2.y;
    float g2 = C0 * r0.z + C1 * r1.z + C2 * r2.z;
    float g3 = C0 * r0.w + C1 * r1.w + C2 * r2.w;
    g0 = floorf(fminf(fmaxf(g0, 0.0f), 255.0f));
    g1 = floorf(fminf(fmaxf(g1, 0.0f), 255.0f));
    g2 = floorf(fminf(fmaxf(g2, 0.0f), 255.0f));
    g3 = floorf(fminf(fmaxf(g3, 0.0f), 255.0f));
    uchar4 st = make_uchar4((unsigned char)g0, (unsigned char)g1,
                            (unsigned char)g2, (unsigned char)g3);
    *(uchar4*)(g + (size_t)b * 262144 + (size_t)rem * 4) = st;
}

// ---------------- K2: Sobel (edge-replicate pad), mag = |gx|+|gy|, dir code --
__global__ __launch_bounds__(256) void k_sobel(const unsigned char* __restrict__ g,
                                               unsigned short* __restrict__ magdir) {
    const float TG22f = (float)0.4142135623730951;
    const float TG67f = (float)2.414213562373095;
    int i = blockIdx.x * 256 + threadIdx.x;     // 4,194,304 pixels
    int b = i >> 18;
    int r = (i >> 9) & 511;
    int w = i & 511;
    const unsigned char* gb = g + (size_t)b * 262144;
    int rm = r > 0 ? r - 1 : 0, rp = r < 511 ? r + 1 : 511;
    int wm = w > 0 ? w - 1 : 0, wp = w < 511 ? w + 1 : 511;
    int a00 = gb[rm * 512 + wm], a01 = gb[rm * 512 + w], a02 = gb[rm * 512 + wp];
    int a10 = gb[r  * 512 + wm],                          a12 = gb[r  * 512 + wp];
    int a20 = gb[rp * 512 + wm], a21 = gb[rp * 512 + w],  a22 = gb[rp * 512 + wp];
    int gx = a02 + 2 * a12 + a22 - a00 - 2 * a10 - a20;
    int gy = a20 + 2 * a21 + a22 - a00 - 2 * a01 - a02;
    int ax = gx < 0 ? -gx : gx;
    int ay = gy < 0 ? -gy : gy;
    int mag = ax + ay;                           // <= 2040, exact
    float fax = (float)ax, fay = (float)ay;
    unsigned dir;
    if (fay <= TG22f * fax)      dir = 0u;                       // horiz
    else if (fay > TG67f * fax)  dir = 1u;                       // vert
    else                         dir = (gx * gy >= 0) ? 2u : 3u; // diag
    magdir[i] = (unsigned short)(mag | (dir << 12));
}

// ---------------- K3: NMS + thresholds, ballot-pack weak/strong bitmasks -----
__global__ __launch_bounds__(256) void k_nms(const unsigned short* __restrict__ magdir,
                                             u64* __restrict__ weakw,
                                             u64* __restrict__ strongw) {
    int i = blockIdx.x * 256 + threadIdx.x;
    int b = i >> 18;
    int r = (i >> 9) & 511;
    int w = i & 511;
    const unsigned short* mb = magdir + (size_t)b * 262144;
    int md  = mb[r * 512 + w];
    int mag = md & 0x7FF;
    int dir = md >> 12;
    auto ldm = [&](int rr, int ww) -> int {
        if ((unsigned)rr > 511u || (unsigned)ww > 511u) return 0;  // zero pad
        return (int)(mb[rr * 512 + ww] & 0x7FF);
    };
    int n1, n2;
    if (dir == 0)      { n1 = ldm(r, w + 1);     n2 = ldm(r, w - 1); }
    else if (dir == 1) { n1 = ldm(r - 1, w);     n2 = ldm(r + 1, w); }
    else if (dir == 2) { n1 = ldm(r - 1, w - 1); n2 = ldm(r + 1, w + 1); }
    else               { n1 = ldm(r - 1, w + 1); n2 = ldm(r + 1, w - 1); }
    bool keep = (mag > n1) && (mag >= n2);
    int nms = keep ? mag : 0;
    u64 wb = __ballot(nms > 50);
    u64 sb = __ballot(nms > 150);
    int widx = ((b << 9) + r) * 8 + (w >> 6);
    int lane = threadIdx.x & 63;
    if (lane == 0) weakw[widx]   = wb;
    else if (lane == 1) strongw[widx] = sb;
}

// ---------------- K4: hysteresis flood fill, block-per-image ----------------
// Division of labor per round:
//   V sweeps (down/up, 4 rows/thread, register carry): IN-WORD vertical,
//     diagonal, horizontal only (carry|dm|self, <<1/>>1). 2 LDS reads/row.
//   H sweep (512 threads own one row): full-width cross-word propagation,
//     with carry widened to (f | rowAbove | rowBelow) so cross-word DIAGONAL
//     connections are carried too.
// Coverage: in-word H/V/diag -> V sweep; cross-word same-row -> H carry;
// cross-word diagonal -> H widened carry. A no-change round is the exact
// fixpoint; all seeds are genuine 8-neighbors AND weak (sound, no overfill).
// Monotone fixpoint => racy/stale/torn LDS reads are valid intermediates.
__device__ inline u64 upfill(u64 w, u64 s) {           // s subset of w
    return ((((w + s) ^ w) & w) | s);
}
__device__ inline u64 runfill(u64 w, u64 s) {
    u64 u = upfill(w, s);
    u64 d = __brevll(upfill(__brevll(w), __brevll(s)));
    return u | d;
}

#define HST 9   // padded LDS row stride (words)

__global__ __launch_bounds__(1024) void k_hyst(const u64* __restrict__ weakg,
                                               const u64* __restrict__ strongg,
                                               u64* __restrict__ edgeg) {
    __shared__ u64 sc[512 * HST];   // cur, row*HST+col  (36.9 KiB)
    __shared__ int sflag[2];
    int b = blockIdx.x;
    int t = threadIdx.x;
    const u64* wk = weakg + (size_t)b * 4096;
    const u64* st = strongg + (size_t)b * 4096;
#pragma unroll
    for (int i = 0; i < 4; ++i) {
        int ig = i * 1024 + t;              // coalesced global
        int r = ig >> 3, c = ig & 7;
        sc[r * HST + c] = st[ig];
    }
    int c  = t & 7;
    int r0 = (t >> 3) * 4;                  // 4 rows per thread (V phase)
    u64 wreg[4];
#pragma unroll
    for (int j = 0; j < 4; ++j) wreg[j] = wk[(r0 + j) * 8 + c];
    u64 hw8[8];                             // H-phase weak row (loop-invariant)
    if (t < 512) {
        const u64* wr = wk + (size_t)t * 8;
#pragma unroll
        for (int c2 = 0; c2 < 8; ++c2) hw8[c2] = wr[c2];
    }
    if (t == 0) { sflag[0] = 0; sflag[1] = 0; }
    __syncthreads();

    int p = 0;
    for (;;) {
        bool ch = false;
        // ---- DOWN sweep (in-word only; cross-word delegated to H) ----
        {
            u64 carry = (r0 > 0) ? sc[(r0 - 1) * HST + c] : 0;
#pragma unroll
            for (int j = 0; j < 4; ++j) {
                int r = r0 + j;
                int idx = r * HST + c;
                u64 wv = wreg[j];
                u64 self = sc[idx];
                if (self == wv) { carry = self; continue; }
                u64 dm = (r < 511) ? sc[idx + HST] : 0;
                u64 vert = carry | dm | self;
                u64 dil = vert | (vert << 1) | (vert >> 1);
                u64 nv = runfill(wv, self | (wv & dil));
                if (nv != self) { sc[idx] = nv; ch = true; }
                carry = nv;
            }
        }
        // ---- UP sweep ----
        {
            u64 carry = (r0 + 4 < 512) ? sc[(r0 + 4) * HST + c] : 0;
#pragma unroll
            for (int j = 3; j >= 0; --j) {
                int r = r0 + j;
                int idx = r * HST + c;
                u64 wv = wreg[j];
                u64 self = sc[idx];
                if (self == wv) { carry = self; continue; }
                u64 um = (r > 0) ? sc[idx - HST] : 0;
                u64 vert = um | carry | self;
                u64 dil = vert | (vert << 1) | (vert >> 1);
                u64 nv = runfill(wv, self | (wv & dil));
                if (nv != self) { sc[idx] = nv; ch = true; }
                carry = nv;
            }
        }
        // ---- H sweep: full-width, cross-word (incl. diagonal via widened carry)
        __syncthreads();                    // V writes visible to row owners
        if (t < 512) {
            u64 m[8], f[8], au[8], ad[8];
            int rowU = (t - 1) * HST, rowD = (t + 1) * HST;
            const bool hU = t > 0, hD = t < 511;
#pragma unroll
            for (int c2 = 0; c2 < 8; ++c2) {
                m[c2]  = sc[t * HST + c2];
                au[c2] = hU ? sc[rowU + c2] : 0;   // racy read: monotone-safe
                ad[c2] = hD ? sc[rowD + c2] : 0;
            }
            u64 carry = 0;                  // bit63 of prev word's {self|up|down}
#pragma unroll
            for (int c2 = 0; c2 < 8; ++c2) {       // L -> R
                u64 s2 = m[c2] | (carry & hw8[c2] & 1ull);
                f[c2] = runfill(hw8[c2], s2);
                carry = (f[c2] | au[c2] | ad[c2]) >> 63;
            }
            carry = 0;                      // bit0 of next word's {self|up|down}
#pragma unroll
            for (int c2 = 7; c2 >= 0; --c2) {      // R -> L
                u64 s2 = f[c2] | ((carry << 63) & hw8[c2]);
                f[c2] = runfill(hw8[c2], s2);
                carry = (f[c2] | au[c2] | ad[c2]) & 1ull;
            }
#pragma unroll
            for (int c2 = 0; c2 < 8; ++c2) {
                if (f[c2] != m[c2]) { sc[t * HST + c2] = f[c2]; ch = true; }
            }
        }
        // ---- convergence: ping-pong flags, 2 syncs total per round ----
        if (ch) sflag[p] = 1;               // benign race (same value)
        if (t == 0) sflag[p ^ 1] = 0;       // prep next round's flag
        __syncthreads();                    // all writes + flags visible
        if (sflag[p] == 0) break;
        p ^= 1;
    }

    u64* eg = edgeg + (size_t)b * 4096;
#pragma unroll
    for (int i = 0; i < 4; ++i) {
        int ig = i * 1024 + t;
        int r = ig >> 3, cc = ig & 7;
        eg[ig] = sc[r * HST + cc];
    }
}

// ---------------- K5: out[b,o,h,w] = relu(W.[x0,x1,x2,edge] + b) -------------
__global__ __launch_bounds__(256) void k_out(const float* __restrict__ x,
                                             const float* __restrict__ Wm,
                                             const float* __restrict__ bv,
                                             const u64* __restrict__ edgeg,
                                             float* __restrict__ out) {
    __shared__ float sW[128];
    __shared__ float sb[32];
    if (threadIdx.x < 128) sW[threadIdx.x] = Wm[threadIdx.x];
    if (threadIdx.x < 32)  sb[threadIdx.x] = bv[threadIdx.x];
    __syncthreads();
    int i   = blockIdx.x * 256 + threadIdx.x;   // 1,048,576 quads
    int b   = i >> 16;
    int rem = i & 65535;                        // h*128 + wq
    size_t pix = (size_t)rem * 4;               // h*512 + wq*4
    const float* xb = x + (size_t)b * 786432;
    float4 x0 = *(const float4*)(xb + pix);
    float4 x1 = *(const float4*)(xb + 262144 + pix);
    float4 x2 = *(const float4*)(xb + 524288 + pix);
    int r  = rem >> 7;
    int wq = rem & 127;
    u64 ew = edgeg[(((size_t)b * 512 + r) * 8) + (wq >> 4)];
    int sh = (wq & 15) * 4;
    float e0 = ((ew >> (sh + 0)) & 1ull) ? 255.0f : 0.0f;
    float e1 = ((ew >> (sh + 1)) & 1ull) ? 255.0f : 0.0f;
    float e2 = ((ew >> (sh + 2)) & 1ull) ? 255.0f : 0.0f;
    float e3 = ((ew >> (sh + 3)) & 1ull) ? 255.0f : 0.0f;
    float* ob = out + (size_t)b * 32 * 262144 + pix;
#pragma unroll 8
    for (int o = 0; o < 32; ++o) {
        float w0 = sW[o * 4 + 0], w1 = sW[o * 4 + 1];
        float w2 = sW[o * 4 + 2], w3 = sW[o * 4 + 3];
        float bb = sb[o];
        fvec4 v;
        v.x = fmaxf(w0 * x0.x + w1 * x1.x + w2 * x2.x + w3 * e0 + bb, 0.0f);
        v.y = fmaxf(w0 * x0.y + w1 * x1.y + w2 * x2.y + w3 * e1 + bb, 0.0f);
        v.z = fmaxf(w0 * x0.z + w1 * x1.z + w2 * x2.z + w3 * e2 + bb, 0.0f);
        v.w = fmaxf(w0 * x0.w + w1 * x1.w + w2 * x2.w + w3 * e3 + bb, 0.0f);
        __builtin_nontemporal_store(v, (fvec4*)(ob + (size_t)o * 262144));
    }
}

extern "C" void kernel_launch(void* const* d_in, const int* in_sizes, int n_in,
                              void* d_out, int out_size, void* d_ws, size_t ws_size,
                              hipStream_t stream) {
    const float* x  = (const float*)d_in[0];   // (16,3,512,512)
    const float* Wm = (const float*)d_in[1];   // (32,4)
    const float* bv = (const float*)d_in[2];   // (32,)
    float* out = (float*)d_out;                // (16,32,512,512)
    char* ws = (char*)d_ws;

    unsigned char*  g      = (unsigned char*)(ws);
    unsigned short* magdir = (unsigned short*)(ws + MD_OFF);
    u64* weakw   = (u64*)(ws + WK_OFF);
    u64* strongw = (u64*)(ws + ST_OFF);
    u64* edgew   = (u64*)(ws + ED_OFF);

    k_gray<<<4096, 256, 0, stream>>>(x, g);
    k_sobel<<<16384, 256, 0, stream>>>(g, magdir);
    k_nms<<<16384, 256, 0, stream>>>(magdir, weakw, strongw);
    k_hyst<<<16, 1024, 0, stream>>>(weakw, strongw, edgew);
    k_out<<<4096, 256, 0, stream>>>(x, Wm, bv, edgew, out);
}